// Round 1
// baseline (656.095 us; speedup 1.0000x reference)
//
#include <hip/hip_runtime.h>
#include <hip/hip_bf16.h>

// GAT 2-layer, N=50000, E=800000, D=128, H=2, F=128, C=H*F=256.
// Strategy: CSR-by-dst built once (dst invariant across layers); per layer:
//   1) fp32 tiled GEMM feat = h@W with fused el/er epilogue
//   2) per-edge score e = leaky_relu(el[src]+er[dst])
//   3) wave-per-node aggregation: max, exp, denom, weighted feat gather-sum
//      (no float atomics; deterministic up to CSR intra-node order)
// Layer-1 out never materialized; h_next = mean over heads computed in-register.

#define NEG_SLOPE 0.2f

// ---------------- CSR build ----------------

__global__ void hist_kernel(const int* __restrict__ dst, int* __restrict__ counts, int n_edges) {
  int e = blockIdx.x * blockDim.x + threadIdx.x;
  if (e < n_edges) atomicAdd(&counts[dst[e]], 1);
}

__global__ __launch_bounds__(1024) void scan_kernel(const int* __restrict__ counts,
                                                    int* __restrict__ offsets,
                                                    int* __restrict__ cursor, int n) {
  __shared__ int wsums[16];
  int t = threadIdx.x;
  int chunk = (n + 1023) >> 10;
  int lo = t * chunk;
  int hi = lo + chunk; if (hi > n) hi = n;
  if (lo > n) lo = n;
  int s = 0;
  for (int i = lo; i < hi; ++i) s += counts[i];
  int lane = t & 63, wid = t >> 6;
  int v = s;
  #pragma unroll
  for (int off = 1; off < 64; off <<= 1) {
    int u = __shfl_up(v, off);
    if (lane >= off) v += u;
  }
  if (lane == 63) wsums[wid] = v;
  __syncthreads();
  if (t < 64) {
    int w = (t < 16) ? wsums[t] : 0;
    #pragma unroll
    for (int off = 1; off < 16; off <<= 1) {
      int u = __shfl_up(w, off);
      if (t >= off) w += u;
    }
    if (t < 16) wsums[t] = w;   // inclusive scan of wave sums
  }
  __syncthreads();
  int base = (wid > 0 ? wsums[wid - 1] : 0) + (v - s);  // exclusive prefix for this thread
  int run = base;
  for (int i = lo; i < hi; ++i) {
    offsets[i] = run;
    cursor[i] = run;
    run += counts[i];
  }
  if (t == 1023) offsets[n] = run;  // last thread's range is empty/ends at n: run == total
}

__global__ void scatter_kernel(const int* __restrict__ dst, int* __restrict__ cursor,
                               int* __restrict__ perm, int n_edges) {
  int e = blockIdx.x * blockDim.x + threadIdx.x;
  if (e < n_edges) {
    int p = atomicAdd(&cursor[dst[e]], 1);
    perm[p] = e;
  }
}

// ---------------- GEMM: feat = h @ W, fused el/er ----------------
// Block: 256 threads; tile: 64 nodes x 256 cols x full K=128.
// LDS: hT[128][64] (k-major, node XOR-swizzled) 32KB + W chunk 16x256 16KB = 48KB.

#define FMA4(A, hv) \
  A.x = fmaf(hv, w4.x, A.x); A.y = fmaf(hv, w4.y, A.y); \
  A.z = fmaf(hv, w4.z, A.z); A.w = fmaf(hv, w4.w, A.w);

__global__ __launch_bounds__(256) void gemm_feat_kernel(
    const float* __restrict__ hin, const float* __restrict__ W,
    const float* __restrict__ al, const float* __restrict__ ar,
    float* __restrict__ feat, float* __restrict__ el, float* __restrict__ er,
    int n_nodes)
{
  __shared__ float hT[128][64];   // [k][node^swz]
  __shared__ float wc[16][256];
  const int tid = threadIdx.x;
  const int node0 = blockIdx.x * 64;

  // load h tile transposed; swizzle node index by ((k>>2)&7)<<2 to spread banks
  #pragma unroll
  for (int r = 0; r < 8; ++r) {
    int q = tid + 256 * r;          // float4 index in [0,2048)
    int node = q >> 5;              // 32 float4 per node row
    int k4 = q & 31;
    int gnode = node0 + node;
    float4 v = make_float4(0.f, 0.f, 0.f, 0.f);
    if (gnode < n_nodes) v = *(const float4*)&hin[(size_t)gnode * 128 + k4 * 4];
    int k = k4 * 4;
    int nn = node ^ ((k4 & 7) << 2);
    hT[k + 0][nn] = v.x;
    hT[k + 1][nn] = v.y;
    hT[k + 2][nn] = v.z;
    hT[k + 3][nn] = v.w;
  }

  const int tidx = tid & 63;   // col group: cols tidx*4 .. +3
  const int tidy = tid >> 6;   // node group: nodes tidy*16 .. +15 (wave-uniform)
  float4 acc[16];
  #pragma unroll
  for (int i = 0; i < 16; ++i) acc[i] = make_float4(0.f, 0.f, 0.f, 0.f);

  for (int kc = 0; kc < 8; ++kc) {
    __syncthreads();
    #pragma unroll
    for (int r = 0; r < 4; ++r) {
      int q = tid + 256 * r;        // float4 index in [0,1024)
      int row = q >> 6;
      int c4 = q & 63;
      *(float4*)&wc[row][c4 * 4] = *(const float4*)&W[(size_t)(kc * 16 + row) * 256 + c4 * 4];
    }
    __syncthreads();
    #pragma unroll
    for (int kk = 0; kk < 16; ++kk) {
      int kg = kc * 16 + kk;
      float4 w4 = *(const float4*)&wc[kk][tidx * 4];
      int sw = ((kg >> 2) & 7) << 2;
      #pragma unroll
      for (int i2 = 0; i2 < 4; ++i2) {
        int nb = (tidy * 16 + i2 * 4) ^ sw;
        float4 h4 = *(const float4*)&hT[kg][nb];   // wave-uniform broadcast
        FMA4(acc[i2 * 4 + 0], h4.x);
        FMA4(acc[i2 * 4 + 1], h4.y);
        FMA4(acc[i2 * 4 + 2], h4.z);
        FMA4(acc[i2 * 4 + 3], h4.w);
      }
    }
  }

  // epilogue: store feat, compute el/er via half-wave reductions
  float4 al4 = *(const float4*)&al[tidx * 4];
  float4 ar4 = *(const float4*)&ar[tidx * 4];
  #pragma unroll
  for (int i = 0; i < 16; ++i) {
    int gnode = node0 + tidy * 16 + i;
    bool ok = gnode < n_nodes;
    if (ok) *(float4*)&feat[(size_t)gnode * 256 + tidx * 4] = acc[i];
    float pl = acc[i].x * al4.x + acc[i].y * al4.y + acc[i].z * al4.z + acc[i].w * al4.w;
    float pr = acc[i].x * ar4.x + acc[i].y * ar4.y + acc[i].z * ar4.z + acc[i].w * ar4.w;
    #pragma unroll
    for (int off = 1; off < 32; off <<= 1) {  // reduce within each 32-lane half (one head)
      pl += __shfl_xor(pl, off);
      pr += __shfl_xor(pr, off);
    }
    if ((tidx & 31) == 0 && ok) {
      int hh = tidx >> 5;
      el[gnode * 2 + hh] = pl;
      er[gnode * 2 + hh] = pr;
    }
  }
}

// ---------------- per-edge scores ----------------

__global__ void edge_kernel(const int* __restrict__ src, const int* __restrict__ dst,
                            const float* __restrict__ el, const float* __restrict__ er,
                            float* __restrict__ ev, int n_edges)
{
  int e = blockIdx.x * blockDim.x + threadIdx.x;
  if (e >= n_edges) return;
  int s = src[e], d = dst[e];
  float2 l = *(const float2*)&el[(size_t)s * 2];
  float2 r = *(const float2*)&er[(size_t)d * 2];
  float v0 = l.x + r.x;
  float v1 = l.y + r.y;
  v0 = (v0 >= 0.f) ? v0 : NEG_SLOPE * v0;
  v1 = (v1 >= 0.f) ? v1 : NEG_SLOPE * v1;
  *(float2*)&ev[(size_t)e * 2] = make_float2(v0, v1);
}

// ---------------- wave-per-node aggregation ----------------
// lane layout over 256 output cols: col = lane*4 + i, i in 0..3; lanes 0-31 = head 0.

__global__ __launch_bounds__(256) void aggregate_kernel(
    const float* __restrict__ feat, const float* __restrict__ ev,
    const int* __restrict__ perm, const int* __restrict__ offsets,
    const int* __restrict__ src, const float* __restrict__ b,
    float* __restrict__ out, float* __restrict__ hnext, int n_nodes)
{
  int node = blockIdx.x * 4 + (threadIdx.x >> 6);
  int lane = threadIdx.x & 63;
  if (node >= n_nodes) return;
  int beg = offsets[node];
  int end = offsets[node + 1];

  // pass 1: per-head max over incoming edges (lanes parallel over edges)
  float m0 = -3.0e38f, m1 = -3.0e38f;
  for (int j = beg + lane; j < end; j += 64) {
    int e = perm[j];
    float2 evv = *(const float2*)&ev[(size_t)e * 2];
    m0 = fmaxf(m0, evv.x);
    m1 = fmaxf(m1, evv.y);
  }
  #pragma unroll
  for (int off = 32; off > 0; off >>= 1) {
    m0 = fmaxf(m0, __shfl_xor(m0, off));
    m1 = fmaxf(m1, __shfl_xor(m1, off));
  }

  // pass 2: weighted sum of feat[src] + denom, edges serial, lanes over 256 cols
  float4 acc = make_float4(0.f, 0.f, 0.f, 0.f);
  float den0 = 0.f, den1 = 0.f;
  int s_n = 0; float2 ev_n = make_float2(0.f, 0.f);
  if (beg < end) {
    int e0 = perm[beg];
    s_n = src[e0];
    ev_n = *(const float2*)&ev[(size_t)e0 * 2];
  }
  for (int j = beg; j < end; ++j) {
    int s = s_n;
    float2 evv = ev_n;
    if (j + 1 < end) {   // prefetch next edge's pointer chain
      int en = perm[j + 1];
      s_n = src[en];
      ev_n = *(const float2*)&ev[(size_t)en * 2];
    }
    float x0 = __expf(evv.x - m0);
    float x1 = __expf(evv.y - m1);
    den0 += x0;
    den1 += x1;
    float4 f4 = *(const float4*)&feat[(size_t)s * 256 + lane * 4];
    float xs = (lane < 32) ? x0 : x1;
    acc.x = fmaf(xs, f4.x, acc.x);
    acc.y = fmaf(xs, f4.y, acc.y);
    acc.z = fmaf(xs, f4.z, acc.z);
    acc.w = fmaf(xs, f4.w, acc.w);
  }

  float4 b4 = *(const float4*)&b[lane * 4];
  float4 o;
  if (end > beg) {
    float inv = 1.0f / ((lane < 32) ? den0 : den1);
    o.x = fmaf(acc.x, inv, b4.x);
    o.y = fmaf(acc.y, inv, b4.y);
    o.z = fmaf(acc.z, inv, b4.z);
    o.w = fmaf(acc.w, inv, b4.w);
  } else {
    o = b4;  // no incoming edges: segment_sum = 0, out = b
  }
  if (out) *(float4*)&out[(size_t)node * 256 + lane * 4] = o;
  if (hnext) {
    // h_next[f] = mean over heads; partner lane is lane^32 (same f, other head)
    float px = __shfl_xor(o.x, 32);
    float py = __shfl_xor(o.y, 32);
    float pz = __shfl_xor(o.z, 32);
    float pw = __shfl_xor(o.w, 32);
    if (lane < 32) {
      float4 hn = make_float4((o.x + px) * 0.5f, (o.y + py) * 0.5f,
                              (o.z + pz) * 0.5f, (o.w + pw) * 0.5f);
      *(float4*)&hnext[(size_t)node * 128 + lane * 4] = hn;
    }
  }
}

// ---------------- launch ----------------

extern "C" void kernel_launch(void* const* d_in, const int* in_sizes, int n_in,
                              void* d_out, int out_size, void* d_ws, size_t ws_size,
                              hipStream_t stream) {
  const float* x   = (const float*)d_in[0];
  const float* Ws  = (const float*)d_in[1];
  const float* als = (const float*)d_in[2];
  const float* ars = (const float*)d_in[3];
  const float* bs  = (const float*)d_in[4];
  const int*   src = (const int*)d_in[5];
  const int*   dst = (const int*)d_in[6];
  const int N = in_sizes[0] / 128;   // 50000
  const int E = in_sizes[5];         // 800000
  float* out = (float*)d_out;

  // workspace carve-out (~88 MB total)
  char* ws = (char*)d_ws;
  auto alloc = [&](size_t bytes) {
    char* p = ws;
    ws += (bytes + 255) & ~(size_t)255;
    return p;
  };
  float* feat    = (float*)alloc((size_t)N * 256 * 4);
  float* hbuf    = (float*)alloc((size_t)N * 128 * 4);
  float* ev      = (float*)alloc((size_t)E * 2 * 4);
  int*   perm    = (int*)alloc((size_t)E * 4);
  int*   offsets = (int*)alloc((size_t)(N + 1) * 4);
  int*   cursor  = (int*)alloc((size_t)N * 4);
  int*   counts  = (int*)alloc((size_t)N * 4);
  float* el      = (float*)alloc((size_t)N * 2 * 4);
  float* er      = (float*)alloc((size_t)N * 2 * 4);

  // CSR by dst (dst is layer-invariant: build once)
  hipMemsetAsync(counts, 0, (size_t)N * 4, stream);
  hist_kernel<<<dim3((E + 255) / 256), dim3(256), 0, stream>>>(dst, counts, E);
  scan_kernel<<<dim3(1), dim3(1024), 0, stream>>>(counts, offsets, cursor, N);
  scatter_kernel<<<dim3((E + 255) / 256), dim3(256), 0, stream>>>(dst, cursor, perm, E);

  for (int l = 0; l < 2; ++l) {
    const float* hin = (l == 0) ? x : hbuf;
    const float* W   = Ws  + (size_t)l * 128 * 256;
    const float* al  = als + (size_t)l * 256;
    const float* ar  = ars + (size_t)l * 256;
    const float* b   = bs  + (size_t)l * 256;
    gemm_feat_kernel<<<dim3((N + 63) / 64), dim3(256), 0, stream>>>(hin, W, al, ar, feat, el, er, N);
    edge_kernel<<<dim3((E + 255) / 256), dim3(256), 0, stream>>>(src, dst, el, er, ev, E);
    aggregate_kernel<<<dim3((N + 3) / 4), dim3(256), 0, stream>>>(
        feat, ev, perm, offsets, src, b,
        (l == 1) ? out : nullptr,
        (l == 0) ? hbuf : nullptr, N);
  }
}

// Round 2
// 509.641 us; speedup vs baseline: 1.2874x; 1.2874x over previous
//
#include <hip/hip_runtime.h>
#include <hip/hip_bf16.h>

// GAT 2-layer, N=50000, E=800000, D=128, H=2, F=128, C=H*F=256.
// Round 2: bf16 feat for the gather path (halves aggregate fetch), CSR-ordered
// edge score/src streams (sequential reads in aggregate), 2-edge unroll.

#define NEG_SLOPE 0.2f

__device__ __forceinline__ unsigned short f2bf(float f) {
  union { float f; unsigned int u; } v; v.f = f;
  unsigned int r = v.u + 0x7FFFu + ((v.u >> 16) & 1u);
  return (unsigned short)(r >> 16);
}
__device__ __forceinline__ float bfbits(unsigned int hi16) {
  union { unsigned int u; float f; } v; v.u = hi16;
  return v.f;
}

// ---------------- CSR build ----------------

__global__ void hist_kernel(const int* __restrict__ dst, int* __restrict__ counts, int n_edges) {
  int e = blockIdx.x * blockDim.x + threadIdx.x;
  if (e < n_edges) atomicAdd(&counts[dst[e]], 1);
}

__global__ __launch_bounds__(1024) void scan_kernel(const int* __restrict__ counts,
                                                    int* __restrict__ offsets,
                                                    int* __restrict__ cursor, int n) {
  __shared__ int wsums[16];
  int t = threadIdx.x;
  int chunk = (n + 1023) >> 10;
  int lo = t * chunk;
  int hi = lo + chunk; if (hi > n) hi = n;
  if (lo > n) lo = n;
  int s = 0;
  for (int i = lo; i < hi; ++i) s += counts[i];
  int lane = t & 63, wid = t >> 6;
  int v = s;
  #pragma unroll
  for (int off = 1; off < 64; off <<= 1) {
    int u = __shfl_up(v, off);
    if (lane >= off) v += u;
  }
  if (lane == 63) wsums[wid] = v;
  __syncthreads();
  if (t < 64) {
    int w = (t < 16) ? wsums[t] : 0;
    #pragma unroll
    for (int off = 1; off < 16; off <<= 1) {
      int u = __shfl_up(w, off);
      if (t >= off) w += u;
    }
    if (t < 16) wsums[t] = w;   // inclusive scan of wave sums
  }
  __syncthreads();
  int base = (wid > 0 ? wsums[wid - 1] : 0) + (v - s);  // exclusive prefix
  int run = base;
  for (int i = lo; i < hi; ++i) {
    offsets[i] = run;
    cursor[i] = run;
    run += counts[i];
  }
  if (t == 1023) offsets[n] = run;
}

__global__ void scatter_kernel(const int* __restrict__ dst, int* __restrict__ cursor,
                               int* __restrict__ perm, int n_edges) {
  int e = blockIdx.x * blockDim.x + threadIdx.x;
  if (e < n_edges) {
    int p = atomicAdd(&cursor[dst[e]], 1);
    perm[p] = e;
  }
}

// ---------------- GEMM: feat = h @ W (bf16 store), fused el/er ----------------

#define FMA4(A, hv) \
  A.x = fmaf(hv, w4.x, A.x); A.y = fmaf(hv, w4.y, A.y); \
  A.z = fmaf(hv, w4.z, A.z); A.w = fmaf(hv, w4.w, A.w);

__global__ __launch_bounds__(256) void gemm_feat_kernel(
    const float* __restrict__ hin, const float* __restrict__ W,
    const float* __restrict__ al, const float* __restrict__ ar,
    unsigned short* __restrict__ featb, float* __restrict__ el, float* __restrict__ er,
    int n_nodes)
{
  __shared__ float hT[128][64];   // [k][node^swz]
  __shared__ float wc[16][256];
  const int tid = threadIdx.x;
  const int node0 = blockIdx.x * 64;

  #pragma unroll
  for (int r = 0; r < 8; ++r) {
    int q = tid + 256 * r;
    int node = q >> 5;
    int k4 = q & 31;
    int gnode = node0 + node;
    float4 v = make_float4(0.f, 0.f, 0.f, 0.f);
    if (gnode < n_nodes) v = *(const float4*)&hin[(size_t)gnode * 128 + k4 * 4];
    int k = k4 * 4;
    int nn = node ^ ((k4 & 7) << 2);
    hT[k + 0][nn] = v.x;
    hT[k + 1][nn] = v.y;
    hT[k + 2][nn] = v.z;
    hT[k + 3][nn] = v.w;
  }

  const int tidx = tid & 63;
  const int tidy = tid >> 6;
  float4 acc[16];
  #pragma unroll
  for (int i = 0; i < 16; ++i) acc[i] = make_float4(0.f, 0.f, 0.f, 0.f);

  for (int kc = 0; kc < 8; ++kc) {
    __syncthreads();
    #pragma unroll
    for (int r = 0; r < 4; ++r) {
      int q = tid + 256 * r;
      int row = q >> 6;
      int c4 = q & 63;
      *(float4*)&wc[row][c4 * 4] = *(const float4*)&W[(size_t)(kc * 16 + row) * 256 + c4 * 4];
    }
    __syncthreads();
    #pragma unroll
    for (int kk = 0; kk < 16; ++kk) {
      int kg = kc * 16 + kk;
      float4 w4 = *(const float4*)&wc[kk][tidx * 4];
      int sw = ((kg >> 2) & 7) << 2;
      #pragma unroll
      for (int i2 = 0; i2 < 4; ++i2) {
        int nb = (tidy * 16 + i2 * 4) ^ sw;
        float4 h4 = *(const float4*)&hT[kg][nb];
        FMA4(acc[i2 * 4 + 0], h4.x);
        FMA4(acc[i2 * 4 + 1], h4.y);
        FMA4(acc[i2 * 4 + 2], h4.z);
        FMA4(acc[i2 * 4 + 3], h4.w);
      }
    }
  }

  float4 al4 = *(const float4*)&al[tidx * 4];
  float4 ar4 = *(const float4*)&ar[tidx * 4];
  #pragma unroll
  for (int i = 0; i < 16; ++i) {
    int gnode = node0 + tidy * 16 + i;
    bool ok = gnode < n_nodes;
    if (ok) {
      ushort4 p;
      p.x = f2bf(acc[i].x); p.y = f2bf(acc[i].y);
      p.z = f2bf(acc[i].z); p.w = f2bf(acc[i].w);
      *(ushort4*)&featb[(size_t)gnode * 256 + tidx * 4] = p;
    }
    float pl = acc[i].x * al4.x + acc[i].y * al4.y + acc[i].z * al4.z + acc[i].w * al4.w;
    float pr = acc[i].x * ar4.x + acc[i].y * ar4.y + acc[i].z * ar4.z + acc[i].w * ar4.w;
    #pragma unroll
    for (int off = 1; off < 32; off <<= 1) {
      pl += __shfl_xor(pl, off);
      pr += __shfl_xor(pr, off);
    }
    if ((tidx & 31) == 0 && ok) {
      int hh = tidx >> 5;
      el[gnode * 2 + hh] = pl;
      er[gnode * 2 + hh] = pr;
    }
  }
}

// ---------------- per-edge scores, written in CSR order ----------------
// evp[j], srcp[j] indexed by CSR position j so the aggregate reads sequentially.

__global__ void eprep_kernel(const int* __restrict__ perm,
                             const int* __restrict__ src, const int* __restrict__ dst,
                             const float* __restrict__ el, const float* __restrict__ er,
                             float* __restrict__ evp, int* __restrict__ srcp, int n_edges)
{
  int j = blockIdx.x * blockDim.x + threadIdx.x;
  if (j >= n_edges) return;
  int e = perm[j];
  int s = src[e], d = dst[e];
  float2 l = *(const float2*)&el[(size_t)s * 2];
  float2 r = *(const float2*)&er[(size_t)d * 2];
  float v0 = l.x + r.x;
  float v1 = l.y + r.y;
  v0 = (v0 >= 0.f) ? v0 : NEG_SLOPE * v0;
  v1 = (v1 >= 0.f) ? v1 : NEG_SLOPE * v1;
  *(float2*)&evp[(size_t)j * 2] = make_float2(v0, v1);
  srcp[j] = s;
}

// ---------------- wave-per-node aggregation ----------------
// lane layout over 256 cols: col = lane*4 + i; lanes 0-31 = head 0.

__global__ __launch_bounds__(256) void aggregate_kernel(
    const unsigned short* __restrict__ featb, const float* __restrict__ evp,
    const int* __restrict__ srcp, const int* __restrict__ offsets,
    const float* __restrict__ b,
    float* __restrict__ out, float* __restrict__ hnext, int n_nodes)
{
  int node = blockIdx.x * 4 + (threadIdx.x >> 6);
  int lane = threadIdx.x & 63;
  if (node >= n_nodes) return;
  int beg = offsets[node];
  int end = offsets[node + 1];

  // pass 1: per-head max (lanes parallel over edges, sequential addresses)
  float m0 = -3.0e38f, m1 = -3.0e38f;
  for (int j = beg + lane; j < end; j += 64) {
    float2 evv = *(const float2*)&evp[(size_t)j * 2];
    m0 = fmaxf(m0, evv.x);
    m1 = fmaxf(m1, evv.y);
  }
  #pragma unroll
  for (int off = 32; off > 0; off >>= 1) {
    m0 = fmaxf(m0, __shfl_xor(m0, off));
    m1 = fmaxf(m1, __shfl_xor(m1, off));
  }

  // pass 2: weighted bf16 feat gather-sum + denom; 2-edge unroll for MLP
  float4 acc = make_float4(0.f, 0.f, 0.f, 0.f);
  float den0 = 0.f, den1 = 0.f;
  int j = beg;
  for (; j + 2 <= end; j += 2) {
    int s0 = srcp[j], s1 = srcp[j + 1];
    float2 ev0 = *(const float2*)&evp[(size_t)j * 2];
    float2 ev1 = *(const float2*)&evp[(size_t)(j + 1) * 2];
    uint2 q0 = *(const uint2*)&featb[(size_t)s0 * 256 + lane * 4];
    uint2 q1 = *(const uint2*)&featb[(size_t)s1 * 256 + lane * 4];
    float x00 = __expf(ev0.x - m0), x01 = __expf(ev0.y - m1);
    float x10 = __expf(ev1.x - m0), x11 = __expf(ev1.y - m1);
    den0 += x00 + x10;
    den1 += x01 + x11;
    float xs0 = (lane < 32) ? x00 : x01;
    float xs1 = (lane < 32) ? x10 : x11;
    acc.x = fmaf(xs0, bfbits(q0.x << 16), acc.x);
    acc.y = fmaf(xs0, bfbits(q0.x & 0xFFFF0000u), acc.y);
    acc.z = fmaf(xs0, bfbits(q0.y << 16), acc.z);
    acc.w = fmaf(xs0, bfbits(q0.y & 0xFFFF0000u), acc.w);
    acc.x = fmaf(xs1, bfbits(q1.x << 16), acc.x);
    acc.y = fmaf(xs1, bfbits(q1.x & 0xFFFF0000u), acc.y);
    acc.z = fmaf(xs1, bfbits(q1.y << 16), acc.z);
    acc.w = fmaf(xs1, bfbits(q1.y & 0xFFFF0000u), acc.w);
  }
  if (j < end) {
    int s0 = srcp[j];
    float2 ev0 = *(const float2*)&evp[(size_t)j * 2];
    uint2 q0 = *(const uint2*)&featb[(size_t)s0 * 256 + lane * 4];
    float x00 = __expf(ev0.x - m0), x01 = __expf(ev0.y - m1);
    den0 += x00;
    den1 += x01;
    float xs0 = (lane < 32) ? x00 : x01;
    acc.x = fmaf(xs0, bfbits(q0.x << 16), acc.x);
    acc.y = fmaf(xs0, bfbits(q0.x & 0xFFFF0000u), acc.y);
    acc.z = fmaf(xs0, bfbits(q0.y << 16), acc.z);
    acc.w = fmaf(xs0, bfbits(q0.y & 0xFFFF0000u), acc.w);
  }

  float4 b4 = *(const float4*)&b[lane * 4];
  float4 o;
  if (end > beg) {
    float inv = 1.0f / ((lane < 32) ? den0 : den1);
    o.x = fmaf(acc.x, inv, b4.x);
    o.y = fmaf(acc.y, inv, b4.y);
    o.z = fmaf(acc.z, inv, b4.z);
    o.w = fmaf(acc.w, inv, b4.w);
  } else {
    o = b4;
  }
  if (out) *(float4*)&out[(size_t)node * 256 + lane * 4] = o;
  if (hnext) {
    float px = __shfl_xor(o.x, 32);
    float py = __shfl_xor(o.y, 32);
    float pz = __shfl_xor(o.z, 32);
    float pw = __shfl_xor(o.w, 32);
    if (lane < 32) {
      float4 hn = make_float4((o.x + px) * 0.5f, (o.y + py) * 0.5f,
                              (o.z + pz) * 0.5f, (o.w + pw) * 0.5f);
      *(float4*)&hnext[(size_t)node * 128 + lane * 4] = hn;
    }
  }
}

// ---------------- launch ----------------

extern "C" void kernel_launch(void* const* d_in, const int* in_sizes, int n_in,
                              void* d_out, int out_size, void* d_ws, size_t ws_size,
                              hipStream_t stream) {
  const float* x   = (const float*)d_in[0];
  const float* Ws  = (const float*)d_in[1];
  const float* als = (const float*)d_in[2];
  const float* ars = (const float*)d_in[3];
  const float* bs  = (const float*)d_in[4];
  const int*   src = (const int*)d_in[5];
  const int*   dst = (const int*)d_in[6];
  const int N = in_sizes[0] / 128;   // 50000
  const int E = in_sizes[5];         // 800000
  float* out = (float*)d_out;

  char* ws = (char*)d_ws;
  auto alloc = [&](size_t bytes) {
    char* p = ws;
    ws += (bytes + 255) & ~(size_t)255;
    return p;
  };
  unsigned short* featb = (unsigned short*)alloc((size_t)N * 256 * 2);
  float* hbuf    = (float*)alloc((size_t)N * 128 * 4);
  float* evp     = (float*)alloc((size_t)E * 2 * 4);
  int*   srcp    = (int*)alloc((size_t)E * 4);
  int*   perm    = (int*)alloc((size_t)E * 4);
  int*   offsets = (int*)alloc((size_t)(N + 1) * 4);
  int*   cursor  = (int*)alloc((size_t)N * 4);
  int*   counts  = (int*)alloc((size_t)N * 4);
  float* el      = (float*)alloc((size_t)N * 2 * 4);
  float* er      = (float*)alloc((size_t)N * 2 * 4);

  // CSR by dst (dst invariant across layers: build once)
  hipMemsetAsync(counts, 0, (size_t)N * 4, stream);
  hist_kernel<<<dim3((E + 255) / 256), dim3(256), 0, stream>>>(dst, counts, E);
  scan_kernel<<<dim3(1), dim3(1024), 0, stream>>>(counts, offsets, cursor, N);
  scatter_kernel<<<dim3((E + 255) / 256), dim3(256), 0, stream>>>(dst, cursor, perm, E);

  for (int l = 0; l < 2; ++l) {
    const float* hin = (l == 0) ? x : hbuf;
    const float* W   = Ws  + (size_t)l * 128 * 256;
    const float* al  = als + (size_t)l * 256;
    const float* ar  = ars + (size_t)l * 256;
    const float* b   = bs  + (size_t)l * 256;
    gemm_feat_kernel<<<dim3((N + 63) / 64), dim3(256), 0, stream>>>(hin, W, al, ar, featb, el, er, N);
    eprep_kernel<<<dim3((E + 255) / 256), dim3(256), 0, stream>>>(perm, src, dst, el, er, evp, srcp, E);
    aggregate_kernel<<<dim3((N + 3) / 4), dim3(256), 0, stream>>>(
        featb, evp, srcp, offsets, b,
        (l == 1) ? out : nullptr,
        (l == 0) ? hbuf : nullptr, N);
  }
}

// Round 3
// 407.156 us; speedup vs baseline: 1.6114x; 1.2517x over previous
//
#include <hip/hip_runtime.h>
#include <hip/hip_bf16.h>

// GAT 2-layer, N=50000, E=800000, D=128, H=2, F=128, C=H*F=256.
// Round 3: hierarchical 3-kernel parallel scan replaces the 111µs single-block
// scan (was the top dispatch). Everything else unchanged from round 2.

#define NEG_SLOPE 0.2f

__device__ __forceinline__ unsigned short f2bf(float f) {
  union { float f; unsigned int u; } v; v.f = f;
  unsigned int r = v.u + 0x7FFFu + ((v.u >> 16) & 1u);
  return (unsigned short)(r >> 16);
}
__device__ __forceinline__ float bfbits(unsigned int hi16) {
  union { unsigned int u; float f; } v; v.u = hi16;
  return v.f;
}

// ---------------- CSR build ----------------

__global__ void hist_kernel(const int* __restrict__ dst, int* __restrict__ counts, int n_edges) {
  int e = blockIdx.x * blockDim.x + threadIdx.x;
  if (e < n_edges) atomicAdd(&counts[dst[e]], 1);
}

// scan1: per-block (1024 elements) sums
__global__ __launch_bounds__(256) void scan1_kernel(const int* __restrict__ counts,
                                                    int* __restrict__ blocksum, int n) {
  __shared__ int wsum[4];
  int t = threadIdx.x;
  int i0 = blockIdx.x * 1024 + t * 4;
  int s = 0;
  if (i0 + 3 < n) {
    int4 c = *(const int4*)&counts[i0];
    s = c.x + c.y + c.z + c.w;
  } else {
    #pragma unroll
    for (int i = 0; i < 4; ++i) if (i0 + i < n) s += counts[i0 + i];
  }
  int v = s;
  #pragma unroll
  for (int off = 1; off < 64; off <<= 1) v += __shfl_xor(v, off);
  if ((t & 63) == 0) wsum[t >> 6] = v;
  __syncthreads();
  if (t == 0) blocksum[blockIdx.x] = wsum[0] + wsum[1] + wsum[2] + wsum[3];
}

// scan2: one block scans up to 256 block sums -> exclusive block offsets + total
__global__ __launch_bounds__(256) void scan2_kernel(const int* __restrict__ blocksum,
                                                    int* __restrict__ blockoff, int nb,
                                                    int* __restrict__ offsets, int n) {
  __shared__ int wsum[4];
  int t = threadIdx.x;
  int v = (t < nb) ? blocksum[t] : 0;
  int lane = t & 63, wid = t >> 6;
  int inc = v;
  #pragma unroll
  for (int off = 1; off < 64; off <<= 1) {
    int u = __shfl_up(inc, off);
    if (lane >= off) inc += u;
  }
  if (lane == 63) wsum[wid] = inc;
  __syncthreads();
  int wbase = 0;
  for (int w = 0; w < wid; ++w) wbase += wsum[w];
  if (t < nb) blockoff[t] = wbase + inc - v;   // exclusive
  if (t == 255) offsets[n] = wbase + inc;      // grand total
}

// scan3: per-block exclusive scan + block offset -> offsets, cursor
__global__ __launch_bounds__(256) void scan3_kernel(const int* __restrict__ counts,
                                                    const int* __restrict__ blockoff,
                                                    int* __restrict__ offsets,
                                                    int* __restrict__ cursor, int n) {
  __shared__ int wsum[4];
  int t = threadIdx.x;
  int i0 = blockIdx.x * 1024 + t * 4;
  int c0 = 0, c1 = 0, c2 = 0, c3 = 0;
  if (i0 + 3 < n) {
    int4 c = *(const int4*)&counts[i0];
    c0 = c.x; c1 = c.y; c2 = c.z; c3 = c.w;
  } else {
    if (i0 + 0 < n) c0 = counts[i0 + 0];
    if (i0 + 1 < n) c1 = counts[i0 + 1];
    if (i0 + 2 < n) c2 = counts[i0 + 2];
    if (i0 + 3 < n) c3 = counts[i0 + 3];
  }
  int s = c0 + c1 + c2 + c3;
  int lane = t & 63, wid = t >> 6;
  int inc = s;
  #pragma unroll
  for (int off = 1; off < 64; off <<= 1) {
    int u = __shfl_up(inc, off);
    if (lane >= off) inc += u;
  }
  if (lane == 63) wsum[wid] = inc;
  __syncthreads();
  int wbase = 0;
  for (int w = 0; w < wid; ++w) wbase += wsum[w];
  int o0 = blockoff[blockIdx.x] + wbase + (inc - s);
  int o1 = o0 + c0, o2 = o1 + c1, o3 = o2 + c2;
  if (i0 + 3 < n) {
    *(int4*)&offsets[i0] = make_int4(o0, o1, o2, o3);
    *(int4*)&cursor[i0]  = make_int4(o0, o1, o2, o3);
  } else {
    if (i0 + 0 < n) { offsets[i0 + 0] = o0; cursor[i0 + 0] = o0; }
    if (i0 + 1 < n) { offsets[i0 + 1] = o1; cursor[i0 + 1] = o1; }
    if (i0 + 2 < n) { offsets[i0 + 2] = o2; cursor[i0 + 2] = o2; }
    if (i0 + 3 < n) { offsets[i0 + 3] = o3; cursor[i0 + 3] = o3; }
  }
}

__global__ void scatter_kernel(const int* __restrict__ dst, int* __restrict__ cursor,
                               int* __restrict__ perm, int n_edges) {
  int e = blockIdx.x * blockDim.x + threadIdx.x;
  if (e < n_edges) {
    int p = atomicAdd(&cursor[dst[e]], 1);
    perm[p] = e;
  }
}

// ---------------- GEMM: feat = h @ W (bf16 store), fused el/er ----------------

#define FMA4(A, hv) \
  A.x = fmaf(hv, w4.x, A.x); A.y = fmaf(hv, w4.y, A.y); \
  A.z = fmaf(hv, w4.z, A.z); A.w = fmaf(hv, w4.w, A.w);

__global__ __launch_bounds__(256) void gemm_feat_kernel(
    const float* __restrict__ hin, const float* __restrict__ W,
    const float* __restrict__ al, const float* __restrict__ ar,
    unsigned short* __restrict__ featb, float* __restrict__ el, float* __restrict__ er,
    int n_nodes)
{
  __shared__ float hT[128][64];   // [k][node^swz]
  __shared__ float wc[16][256];
  const int tid = threadIdx.x;
  const int node0 = blockIdx.x * 64;

  #pragma unroll
  for (int r = 0; r < 8; ++r) {
    int q = tid + 256 * r;
    int node = q >> 5;
    int k4 = q & 31;
    int gnode = node0 + node;
    float4 v = make_float4(0.f, 0.f, 0.f, 0.f);
    if (gnode < n_nodes) v = *(const float4*)&hin[(size_t)gnode * 128 + k4 * 4];
    int k = k4 * 4;
    int nn = node ^ ((k4 & 7) << 2);
    hT[k + 0][nn] = v.x;
    hT[k + 1][nn] = v.y;
    hT[k + 2][nn] = v.z;
    hT[k + 3][nn] = v.w;
  }

  const int tidx = tid & 63;
  const int tidy = tid >> 6;
  float4 acc[16];
  #pragma unroll
  for (int i = 0; i < 16; ++i) acc[i] = make_float4(0.f, 0.f, 0.f, 0.f);

  for (int kc = 0; kc < 8; ++kc) {
    __syncthreads();
    #pragma unroll
    for (int r = 0; r < 4; ++r) {
      int q = tid + 256 * r;
      int row = q >> 6;
      int c4 = q & 63;
      *(float4*)&wc[row][c4 * 4] = *(const float4*)&W[(size_t)(kc * 16 + row) * 256 + c4 * 4];
    }
    __syncthreads();
    #pragma unroll
    for (int kk = 0; kk < 16; ++kk) {
      int kg = kc * 16 + kk;
      float4 w4 = *(const float4*)&wc[kk][tidx * 4];
      int sw = ((kg >> 2) & 7) << 2;
      #pragma unroll
      for (int i2 = 0; i2 < 4; ++i2) {
        int nb = (tidy * 16 + i2 * 4) ^ sw;
        float4 h4 = *(const float4*)&hT[kg][nb];
        FMA4(acc[i2 * 4 + 0], h4.x);
        FMA4(acc[i2 * 4 + 1], h4.y);
        FMA4(acc[i2 * 4 + 2], h4.z);
        FMA4(acc[i2 * 4 + 3], h4.w);
      }
    }
  }

  float4 al4 = *(const float4*)&al[tidx * 4];
  float4 ar4 = *(const float4*)&ar[tidx * 4];
  #pragma unroll
  for (int i = 0; i < 16; ++i) {
    int gnode = node0 + tidy * 16 + i;
    bool ok = gnode < n_nodes;
    if (ok) {
      ushort4 p;
      p.x = f2bf(acc[i].x); p.y = f2bf(acc[i].y);
      p.z = f2bf(acc[i].z); p.w = f2bf(acc[i].w);
      *(ushort4*)&featb[(size_t)gnode * 256 + tidx * 4] = p;
    }
    float pl = acc[i].x * al4.x + acc[i].y * al4.y + acc[i].z * al4.z + acc[i].w * al4.w;
    float pr = acc[i].x * ar4.x + acc[i].y * ar4.y + acc[i].z * ar4.z + acc[i].w * ar4.w;
    #pragma unroll
    for (int off = 1; off < 32; off <<= 1) {
      pl += __shfl_xor(pl, off);
      pr += __shfl_xor(pr, off);
    }
    if ((tidx & 31) == 0 && ok) {
      int hh = tidx >> 5;
      el[gnode * 2 + hh] = pl;
      er[gnode * 2 + hh] = pr;
    }
  }
}

// ---------------- per-edge scores, written in CSR order ----------------

__global__ void eprep_kernel(const int* __restrict__ perm,
                             const int* __restrict__ src, const int* __restrict__ dst,
                             const float* __restrict__ el, const float* __restrict__ er,
                             float* __restrict__ evp, int* __restrict__ srcp, int n_edges)
{
  int j = blockIdx.x * blockDim.x + threadIdx.x;
  if (j >= n_edges) return;
  int e = perm[j];
  int s = src[e], d = dst[e];
  float2 l = *(const float2*)&el[(size_t)s * 2];
  float2 r = *(const float2*)&er[(size_t)d * 2];
  float v0 = l.x + r.x;
  float v1 = l.y + r.y;
  v0 = (v0 >= 0.f) ? v0 : NEG_SLOPE * v0;
  v1 = (v1 >= 0.f) ? v1 : NEG_SLOPE * v1;
  *(float2*)&evp[(size_t)j * 2] = make_float2(v0, v1);
  srcp[j] = s;
}

// ---------------- wave-per-node aggregation ----------------

__global__ __launch_bounds__(256) void aggregate_kernel(
    const unsigned short* __restrict__ featb, const float* __restrict__ evp,
    const int* __restrict__ srcp, const int* __restrict__ offsets,
    const float* __restrict__ b,
    float* __restrict__ out, float* __restrict__ hnext, int n_nodes)
{
  int node = blockIdx.x * 4 + (threadIdx.x >> 6);
  int lane = threadIdx.x & 63;
  if (node >= n_nodes) return;
  int beg = offsets[node];
  int end = offsets[node + 1];

  // pass 1: per-head max (lanes parallel over edges, sequential addresses)
  float m0 = -3.0e38f, m1 = -3.0e38f;
  for (int j = beg + lane; j < end; j += 64) {
    float2 evv = *(const float2*)&evp[(size_t)j * 2];
    m0 = fmaxf(m0, evv.x);
    m1 = fmaxf(m1, evv.y);
  }
  #pragma unroll
  for (int off = 32; off > 0; off >>= 1) {
    m0 = fmaxf(m0, __shfl_xor(m0, off));
    m1 = fmaxf(m1, __shfl_xor(m1, off));
  }

  // pass 2: weighted bf16 feat gather-sum + denom; 2-edge unroll
  float4 acc = make_float4(0.f, 0.f, 0.f, 0.f);
  float den0 = 0.f, den1 = 0.f;
  int j = beg;
  for (; j + 2 <= end; j += 2) {
    int s0 = srcp[j], s1 = srcp[j + 1];
    float2 ev0 = *(const float2*)&evp[(size_t)j * 2];
    float2 ev1 = *(const float2*)&evp[(size_t)(j + 1) * 2];
    uint2 q0 = *(const uint2*)&featb[(size_t)s0 * 256 + lane * 4];
    uint2 q1 = *(const uint2*)&featb[(size_t)s1 * 256 + lane * 4];
    float x00 = __expf(ev0.x - m0), x01 = __expf(ev0.y - m1);
    float x10 = __expf(ev1.x - m0), x11 = __expf(ev1.y - m1);
    den0 += x00 + x10;
    den1 += x01 + x11;
    float xs0 = (lane < 32) ? x00 : x01;
    float xs1 = (lane < 32) ? x10 : x11;
    acc.x = fmaf(xs0, bfbits(q0.x << 16), acc.x);
    acc.y = fmaf(xs0, bfbits(q0.x & 0xFFFF0000u), acc.y);
    acc.z = fmaf(xs0, bfbits(q0.y << 16), acc.z);
    acc.w = fmaf(xs0, bfbits(q0.y & 0xFFFF0000u), acc.w);
    acc.x = fmaf(xs1, bfbits(q1.x << 16), acc.x);
    acc.y = fmaf(xs1, bfbits(q1.x & 0xFFFF0000u), acc.y);
    acc.z = fmaf(xs1, bfbits(q1.y << 16), acc.z);
    acc.w = fmaf(xs1, bfbits(q1.y & 0xFFFF0000u), acc.w);
  }
  if (j < end) {
    int s0 = srcp[j];
    float2 ev0 = *(const float2*)&evp[(size_t)j * 2];
    uint2 q0 = *(const uint2*)&featb[(size_t)s0 * 256 + lane * 4];
    float x00 = __expf(ev0.x - m0), x01 = __expf(ev0.y - m1);
    den0 += x00;
    den1 += x01;
    float xs0 = (lane < 32) ? x00 : x01;
    acc.x = fmaf(xs0, bfbits(q0.x << 16), acc.x);
    acc.y = fmaf(xs0, bfbits(q0.x & 0xFFFF0000u), acc.y);
    acc.z = fmaf(xs0, bfbits(q0.y << 16), acc.z);
    acc.w = fmaf(xs0, bfbits(q0.y & 0xFFFF0000u), acc.w);
  }

  float4 b4 = *(const float4*)&b[lane * 4];
  float4 o;
  if (end > beg) {
    float inv = 1.0f / ((lane < 32) ? den0 : den1);
    o.x = fmaf(acc.x, inv, b4.x);
    o.y = fmaf(acc.y, inv, b4.y);
    o.z = fmaf(acc.z, inv, b4.z);
    o.w = fmaf(acc.w, inv, b4.w);
  } else {
    o = b4;
  }
  if (out) *(float4*)&out[(size_t)node * 256 + lane * 4] = o;
  if (hnext) {
    float px = __shfl_xor(o.x, 32);
    float py = __shfl_xor(o.y, 32);
    float pz = __shfl_xor(o.z, 32);
    float pw = __shfl_xor(o.w, 32);
    if (lane < 32) {
      float4 hn = make_float4((o.x + px) * 0.5f, (o.y + py) * 0.5f,
                              (o.z + pz) * 0.5f, (o.w + pw) * 0.5f);
      *(float4*)&hnext[(size_t)node * 128 + lane * 4] = hn;
    }
  }
}

// ---------------- launch ----------------

extern "C" void kernel_launch(void* const* d_in, const int* in_sizes, int n_in,
                              void* d_out, int out_size, void* d_ws, size_t ws_size,
                              hipStream_t stream) {
  const float* x   = (const float*)d_in[0];
  const float* Ws  = (const float*)d_in[1];
  const float* als = (const float*)d_in[2];
  const float* ars = (const float*)d_in[3];
  const float* bs  = (const float*)d_in[4];
  const int*   src = (const int*)d_in[5];
  const int*   dst = (const int*)d_in[6];
  const int N = in_sizes[0] / 128;   // 50000
  const int E = in_sizes[5];         // 800000
  float* out = (float*)d_out;

  char* ws = (char*)d_ws;
  auto alloc = [&](size_t bytes) {
    char* p = ws;
    ws += (bytes + 255) & ~(size_t)255;
    return p;
  };
  unsigned short* featb = (unsigned short*)alloc((size_t)N * 256 * 2);
  float* hbuf    = (float*)alloc((size_t)N * 128 * 4);
  float* evp     = (float*)alloc((size_t)E * 2 * 4);
  int*   srcp    = (int*)alloc((size_t)E * 4);
  int*   perm    = (int*)alloc((size_t)E * 4);
  int*   offsets = (int*)alloc((size_t)(N + 1) * 4);
  int*   cursor  = (int*)alloc((size_t)N * 4);
  int*   counts  = (int*)alloc((size_t)N * 4);
  float* el      = (float*)alloc((size_t)N * 2 * 4);
  float* er      = (float*)alloc((size_t)N * 2 * 4);
  int*   blocksum = (int*)alloc((size_t)256 * 4);
  int*   blockoff = (int*)alloc((size_t)256 * 4);

  const int nb = (N + 1023) / 1024;  // 49 (<=256 supported by scan2)

  // CSR by dst (dst invariant across layers: build once)
  hipMemsetAsync(counts, 0, (size_t)N * 4, stream);
  hist_kernel<<<dim3((E + 255) / 256), dim3(256), 0, stream>>>(dst, counts, E);
  scan1_kernel<<<dim3(nb), dim3(256), 0, stream>>>(counts, blocksum, N);
  scan2_kernel<<<dim3(1), dim3(256), 0, stream>>>(blocksum, blockoff, nb, offsets, N);
  scan3_kernel<<<dim3(nb), dim3(256), 0, stream>>>(counts, blockoff, offsets, cursor, N);
  scatter_kernel<<<dim3((E + 255) / 256), dim3(256), 0, stream>>>(dst, cursor, perm, E);

  for (int l = 0; l < 2; ++l) {
    const float* hin = (l == 0) ? x : hbuf;
    const float* W   = Ws  + (size_t)l * 128 * 256;
    const float* al  = als + (size_t)l * 256;
    const float* ar  = ars + (size_t)l * 256;
    const float* b   = bs  + (size_t)l * 256;
    gemm_feat_kernel<<<dim3((N + 63) / 64), dim3(256), 0, stream>>>(hin, W, al, ar, featb, el, er, N);
    eprep_kernel<<<dim3((E + 255) / 256), dim3(256), 0, stream>>>(perm, src, dst, el, er, evp, srcp, E);
    aggregate_kernel<<<dim3((N + 3) / 4), dim3(256), 0, stream>>>(
        featb, evp, srcp, offsets, b,
        (l == 1) ? out : nullptr,
        (l == 0) ? hbuf : nullptr, N);
  }
}

// Round 4
// 345.711 us; speedup vs baseline: 1.8978x; 1.1777x over previous
//
#include <hip/hip_runtime.h>
#include <hip/hip_bf16.h>

// GAT 2-layer, N=50000, E=800000, D=128, H=2, F=128, C=H*F=256.
// Round 4: MFMA bf16x3 GEMM (fp32-equivalent accuracy) replaces the fp32
// vector-ALU GEMM (was 2x87us, VALUBusy 33%). Zero-LDS: A-frags direct from
// global fp32 (split hi/lo in-register), B-frags from pre-packed bf16 hi/lo
// in fragment order (L2-resident). el/er fused on fp32 accumulators.
// CSR build / eprep / aggregate unchanged from round 3.

#define NEG_SLOPE 0.2f

typedef __attribute__((ext_vector_type(8))) short bf16x8_t;
typedef __attribute__((ext_vector_type(4))) float f32x4_t;

__device__ __forceinline__ unsigned short f2bf(float f) {
  union { float f; unsigned int u; } v; v.f = f;
  unsigned int r = v.u + 0x7FFFu + ((v.u >> 16) & 1u);
  return (unsigned short)(r >> 16);
}
__device__ __forceinline__ float bfbits(unsigned int hi16) {
  union { unsigned int u; float f; } v; v.u = hi16;
  return v.f;
}

// ---------------- CSR build ----------------

__global__ void hist_kernel(const int* __restrict__ dst, int* __restrict__ counts, int n_edges) {
  int e = blockIdx.x * blockDim.x + threadIdx.x;
  if (e < n_edges) atomicAdd(&counts[dst[e]], 1);
}

__global__ __launch_bounds__(256) void scan1_kernel(const int* __restrict__ counts,
                                                    int* __restrict__ blocksum, int n) {
  __shared__ int wsum[4];
  int t = threadIdx.x;
  int i0 = blockIdx.x * 1024 + t * 4;
  int s = 0;
  if (i0 + 3 < n) {
    int4 c = *(const int4*)&counts[i0];
    s = c.x + c.y + c.z + c.w;
  } else {
    #pragma unroll
    for (int i = 0; i < 4; ++i) if (i0 + i < n) s += counts[i0 + i];
  }
  int v = s;
  #pragma unroll
  for (int off = 1; off < 64; off <<= 1) v += __shfl_xor(v, off);
  if ((t & 63) == 0) wsum[t >> 6] = v;
  __syncthreads();
  if (t == 0) blocksum[blockIdx.x] = wsum[0] + wsum[1] + wsum[2] + wsum[3];
}

__global__ __launch_bounds__(256) void scan2_kernel(const int* __restrict__ blocksum,
                                                    int* __restrict__ blockoff, int nb,
                                                    int* __restrict__ offsets, int n) {
  __shared__ int wsum[4];
  int t = threadIdx.x;
  int v = (t < nb) ? blocksum[t] : 0;
  int lane = t & 63, wid = t >> 6;
  int inc = v;
  #pragma unroll
  for (int off = 1; off < 64; off <<= 1) {
    int u = __shfl_up(inc, off);
    if (lane >= off) inc += u;
  }
  if (lane == 63) wsum[wid] = inc;
  __syncthreads();
  int wbase = 0;
  for (int w = 0; w < wid; ++w) wbase += wsum[w];
  if (t < nb) blockoff[t] = wbase + inc - v;   // exclusive
  if (t == 255) offsets[n] = wbase + inc;      // grand total
}

__global__ __launch_bounds__(256) void scan3_kernel(const int* __restrict__ counts,
                                                    const int* __restrict__ blockoff,
                                                    int* __restrict__ offsets,
                                                    int* __restrict__ cursor, int n) {
  __shared__ int wsum[4];
  int t = threadIdx.x;
  int i0 = blockIdx.x * 1024 + t * 4;
  int c0 = 0, c1 = 0, c2 = 0, c3 = 0;
  if (i0 + 3 < n) {
    int4 c = *(const int4*)&counts[i0];
    c0 = c.x; c1 = c.y; c2 = c.z; c3 = c.w;
  } else {
    if (i0 + 0 < n) c0 = counts[i0 + 0];
    if (i0 + 1 < n) c1 = counts[i0 + 1];
    if (i0 + 2 < n) c2 = counts[i0 + 2];
    if (i0 + 3 < n) c3 = counts[i0 + 3];
  }
  int s = c0 + c1 + c2 + c3;
  int lane = t & 63, wid = t >> 6;
  int inc = s;
  #pragma unroll
  for (int off = 1; off < 64; off <<= 1) {
    int u = __shfl_up(inc, off);
    if (lane >= off) inc += u;
  }
  if (lane == 63) wsum[wid] = inc;
  __syncthreads();
  int wbase = 0;
  for (int w = 0; w < wid; ++w) wbase += wsum[w];
  int o0 = blockoff[blockIdx.x] + wbase + (inc - s);
  int o1 = o0 + c0, o2 = o1 + c1, o3 = o2 + c2;
  if (i0 + 3 < n) {
    *(int4*)&offsets[i0] = make_int4(o0, o1, o2, o3);
    *(int4*)&cursor[i0]  = make_int4(o0, o1, o2, o3);
  } else {
    if (i0 + 0 < n) { offsets[i0 + 0] = o0; cursor[i0 + 0] = o0; }
    if (i0 + 1 < n) { offsets[i0 + 1] = o1; cursor[i0 + 1] = o1; }
    if (i0 + 2 < n) { offsets[i0 + 2] = o2; cursor[i0 + 2] = o2; }
    if (i0 + 3 < n) { offsets[i0 + 3] = o3; cursor[i0 + 3] = o3; }
  }
}

__global__ void scatter_kernel(const int* __restrict__ dst, int* __restrict__ cursor,
                               int* __restrict__ perm, int n_edges) {
  int e = blockIdx.x * blockDim.x + threadIdx.x;
  if (e < n_edges) {
    int p = atomicAdd(&cursor[dst[e]], 1);
    perm[p] = e;
  }
}

// ---------------- W pack: fp32 -> bf16 hi/lo in B-fragment order ----------------
// Wpack[lay][s][ct][lane][j] : lane holds B[k=s*32+(lane>>4)*8+j][col=ct*16+(lane&15)]

__global__ __launch_bounds__(256) void wpack_kernel(const float* __restrict__ Ws,
                                                    unsigned short* __restrict__ Whi,
                                                    unsigned short* __restrict__ Wlo) {
  int t = blockIdx.x * 256 + threadIdx.x;   // 8192 threads: 2 lay x 4 s x 16 ct x 64 lane
  int lane = t & 63;
  int ct = (t >> 6) & 15;
  int s = (t >> 10) & 3;
  int lay = t >> 12;
  int col = ct * 16 + (lane & 15);
  int kbase = s * 32 + (lane >> 4) * 8;
  size_t obase = (size_t)t * 8;
  #pragma unroll
  for (int j = 0; j < 8; ++j) {
    float w = Ws[(size_t)lay * 32768 + (size_t)(kbase + j) * 256 + col];
    unsigned short hb = f2bf(w);
    float rem = w - bfbits((unsigned int)hb << 16);
    Whi[obase + j] = hb;
    Wlo[obase + j] = f2bf(rem);
  }
}

// ---------------- MFMA GEMM: feat = h @ W (bf16x3), fused el/er ----------------
// Block 256 thr = 4 waves; block tile 64 nodes x 256 cols; wave: 16 rows x 256.
// A frag: row=lane&15, k=(lane>>4)*8+j (fp32 loads, hi/lo split in-register).
// C/D frag: col=lane&15, row=(lane>>4)*4+reg.

__global__ __launch_bounds__(256) void gemm_feat_kernel(
    const float* __restrict__ hin,
    const unsigned short* __restrict__ Whi, const unsigned short* __restrict__ Wlo,
    const float* __restrict__ al, const float* __restrict__ ar,
    unsigned short* __restrict__ featb, float* __restrict__ el, float* __restrict__ er,
    int n_nodes)
{
  const int tid = threadIdx.x;
  const int w = tid >> 6;
  const int lane = tid & 63;
  const int lrow = lane & 15;
  const int g = lane >> 4;
  const int node0 = blockIdx.x * 64 + w * 16;

  f32x4_t acc[16];
  #pragma unroll
  for (int i = 0; i < 16; ++i) acc[i] = (f32x4_t){0.f, 0.f, 0.f, 0.f};

  int arow = node0 + lrow;
  int arow_c = (arow < n_nodes) ? arow : (n_nodes - 1);
  const float* aptr = hin + (size_t)arow_c * 128 + g * 8;

  for (int s = 0; s < 4; ++s) {
    float4 f0 = *(const float4*)(aptr + s * 32);
    float4 f1 = *(const float4*)(aptr + s * 32 + 4);
    float fv[8] = {f0.x, f0.y, f0.z, f0.w, f1.x, f1.y, f1.z, f1.w};
    bf16x8_t ahi, alo;
    #pragma unroll
    for (int j = 0; j < 8; ++j) {
      unsigned short hb = f2bf(fv[j]);
      float rem = fv[j] - bfbits((unsigned int)hb << 16);
      ahi[j] = (short)hb;
      alo[j] = (short)f2bf(rem);
    }
    const unsigned short* bh_p = Whi + ((size_t)(s * 16) * 64 + lane) * 8;
    const unsigned short* bl_p = Wlo + ((size_t)(s * 16) * 64 + lane) * 8;
    #pragma unroll
    for (int ct = 0; ct < 16; ++ct) {
      bf16x8_t bh = *(const bf16x8_t*)(bh_p + (size_t)ct * 512);
      bf16x8_t bl = *(const bf16x8_t*)(bl_p + (size_t)ct * 512);
      acc[ct] = __builtin_amdgcn_mfma_f32_16x16x32_bf16(ahi, bh, acc[ct], 0, 0, 0);
      acc[ct] = __builtin_amdgcn_mfma_f32_16x16x32_bf16(alo, bh, acc[ct], 0, 0, 0);
      acc[ct] = __builtin_amdgcn_mfma_f32_16x16x32_bf16(ahi, bl, acc[ct], 0, 0, 0);
    }
  }

  // epilogue: al/ar per lane-col, feat bf16 store, el/er via 16-lane-group reduce
  float alc[16], arc[16];
  #pragma unroll
  for (int ct = 0; ct < 16; ++ct) {
    alc[ct] = al[ct * 16 + lrow];
    arc[ct] = ar[ct * 16 + lrow];
  }
  #pragma unroll
  for (int r = 0; r < 4; ++r) {
    int orow = node0 + g * 4 + r;
    bool ok = orow < n_nodes;
    float pl0 = 0.f, pl1 = 0.f, pr0 = 0.f, pr1 = 0.f;
    #pragma unroll
    for (int ct = 0; ct < 16; ++ct) {
      float v = acc[ct][r];
      if (ct < 8) { pl0 += v * alc[ct]; pr0 += v * arc[ct]; }
      else        { pl1 += v * alc[ct]; pr1 += v * arc[ct]; }
      if (ok) featb[(size_t)orow * 256 + ct * 16 + lrow] = f2bf(v);
    }
    #pragma unroll
    for (int off = 1; off < 16; off <<= 1) {
      pl0 += __shfl_xor(pl0, off);
      pl1 += __shfl_xor(pl1, off);
      pr0 += __shfl_xor(pr0, off);
      pr1 += __shfl_xor(pr1, off);
    }
    if (lrow == 0 && ok) {
      *(float2*)&el[(size_t)orow * 2] = make_float2(pl0, pl1);
      *(float2*)&er[(size_t)orow * 2] = make_float2(pr0, pr1);
    }
  }
}

// ---------------- per-edge scores, written in CSR order ----------------

__global__ void eprep_kernel(const int* __restrict__ perm,
                             const int* __restrict__ src, const int* __restrict__ dst,
                             const float* __restrict__ el, const float* __restrict__ er,
                             float* __restrict__ evp, int* __restrict__ srcp, int n_edges)
{
  int j = blockIdx.x * blockDim.x + threadIdx.x;
  if (j >= n_edges) return;
  int e = perm[j];
  int s = src[e], d = dst[e];
  float2 l = *(const float2*)&el[(size_t)s * 2];
  float2 r = *(const float2*)&er[(size_t)d * 2];
  float v0 = l.x + r.x;
  float v1 = l.y + r.y;
  v0 = (v0 >= 0.f) ? v0 : NEG_SLOPE * v0;
  v1 = (v1 >= 0.f) ? v1 : NEG_SLOPE * v1;
  *(float2*)&evp[(size_t)j * 2] = make_float2(v0, v1);
  srcp[j] = s;
}

// ---------------- wave-per-node aggregation ----------------

__global__ __launch_bounds__(256) void aggregate_kernel(
    const unsigned short* __restrict__ featb, const float* __restrict__ evp,
    const int* __restrict__ srcp, const int* __restrict__ offsets,
    const float* __restrict__ b,
    float* __restrict__ out, float* __restrict__ hnext, int n_nodes)
{
  int node = blockIdx.x * 4 + (threadIdx.x >> 6);
  int lane = threadIdx.x & 63;
  if (node >= n_nodes) return;
  int beg = offsets[node];
  int end = offsets[node + 1];

  float m0 = -3.0e38f, m1 = -3.0e38f;
  for (int j = beg + lane; j < end; j += 64) {
    float2 evv = *(const float2*)&evp[(size_t)j * 2];
    m0 = fmaxf(m0, evv.x);
    m1 = fmaxf(m1, evv.y);
  }
  #pragma unroll
  for (int off = 32; off > 0; off >>= 1) {
    m0 = fmaxf(m0, __shfl_xor(m0, off));
    m1 = fmaxf(m1, __shfl_xor(m1, off));
  }

  float4 acc = make_float4(0.f, 0.f, 0.f, 0.f);
  float den0 = 0.f, den1 = 0.f;
  int j = beg;
  for (; j + 2 <= end; j += 2) {
    int s0 = srcp[j], s1 = srcp[j + 1];
    float2 ev0 = *(const float2*)&evp[(size_t)j * 2];
    float2 ev1 = *(const float2*)&evp[(size_t)(j + 1) * 2];
    uint2 q0 = *(const uint2*)&featb[(size_t)s0 * 256 + lane * 4];
    uint2 q1 = *(const uint2*)&featb[(size_t)s1 * 256 + lane * 4];
    float x00 = __expf(ev0.x - m0), x01 = __expf(ev0.y - m1);
    float x10 = __expf(ev1.x - m0), x11 = __expf(ev1.y - m1);
    den0 += x00 + x10;
    den1 += x01 + x11;
    float xs0 = (lane < 32) ? x00 : x01;
    float xs1 = (lane < 32) ? x10 : x11;
    acc.x = fmaf(xs0, bfbits(q0.x << 16), acc.x);
    acc.y = fmaf(xs0, bfbits(q0.x & 0xFFFF0000u), acc.y);
    acc.z = fmaf(xs0, bfbits(q0.y << 16), acc.z);
    acc.w = fmaf(xs0, bfbits(q0.y & 0xFFFF0000u), acc.w);
    acc.x = fmaf(xs1, bfbits(q1.x << 16), acc.x);
    acc.y = fmaf(xs1, bfbits(q1.x & 0xFFFF0000u), acc.y);
    acc.z = fmaf(xs1, bfbits(q1.y << 16), acc.z);
    acc.w = fmaf(xs1, bfbits(q1.y & 0xFFFF0000u), acc.w);
  }
  if (j < end) {
    int s0 = srcp[j];
    float2 ev0 = *(const float2*)&evp[(size_t)j * 2];
    uint2 q0 = *(const uint2*)&featb[(size_t)s0 * 256 + lane * 4];
    float x00 = __expf(ev0.x - m0), x01 = __expf(ev0.y - m1);
    den0 += x00;
    den1 += x01;
    float xs0 = (lane < 32) ? x00 : x01;
    acc.x = fmaf(xs0, bfbits(q0.x << 16), acc.x);
    acc.y = fmaf(xs0, bfbits(q0.x & 0xFFFF0000u), acc.y);
    acc.z = fmaf(xs0, bfbits(q0.y << 16), acc.z);
    acc.w = fmaf(xs0, bfbits(q0.y & 0xFFFF0000u), acc.w);
  }

  float4 b4 = *(const float4*)&b[lane * 4];
  float4 o;
  if (end > beg) {
    float inv = 1.0f / ((lane < 32) ? den0 : den1);
    o.x = fmaf(acc.x, inv, b4.x);
    o.y = fmaf(acc.y, inv, b4.y);
    o.z = fmaf(acc.z, inv, b4.z);
    o.w = fmaf(acc.w, inv, b4.w);
  } else {
    o = b4;
  }
  if (out) *(float4*)&out[(size_t)node * 256 + lane * 4] = o;
  if (hnext) {
    float px = __shfl_xor(o.x, 32);
    float py = __shfl_xor(o.y, 32);
    float pz = __shfl_xor(o.z, 32);
    float pw = __shfl_xor(o.w, 32);
    if (lane < 32) {
      float4 hn = make_float4((o.x + px) * 0.5f, (o.y + py) * 0.5f,
                              (o.z + pz) * 0.5f, (o.w + pw) * 0.5f);
      *(float4*)&hnext[(size_t)node * 128 + lane * 4] = hn;
    }
  }
}

// ---------------- launch ----------------

extern "C" void kernel_launch(void* const* d_in, const int* in_sizes, int n_in,
                              void* d_out, int out_size, void* d_ws, size_t ws_size,
                              hipStream_t stream) {
  const float* x   = (const float*)d_in[0];
  const float* Ws  = (const float*)d_in[1];
  const float* als = (const float*)d_in[2];
  const float* ars = (const float*)d_in[3];
  const float* bs  = (const float*)d_in[4];
  const int*   src = (const int*)d_in[5];
  const int*   dst = (const int*)d_in[6];
  const int N = in_sizes[0] / 128;   // 50000
  const int E = in_sizes[5];         // 800000
  float* out = (float*)d_out;

  char* ws = (char*)d_ws;
  auto alloc = [&](size_t bytes) {
    char* p = ws;
    ws += (bytes + 255) & ~(size_t)255;
    return p;
  };
  unsigned short* featb = (unsigned short*)alloc((size_t)N * 256 * 2);
  float* hbuf    = (float*)alloc((size_t)N * 128 * 4);
  float* evp     = (float*)alloc((size_t)E * 2 * 4);
  int*   srcp    = (int*)alloc((size_t)E * 4);
  int*   perm    = (int*)alloc((size_t)E * 4);
  int*   offsets = (int*)alloc((size_t)(N + 1) * 4);
  int*   cursor  = (int*)alloc((size_t)N * 4);
  int*   counts  = (int*)alloc((size_t)N * 4);
  float* el      = (float*)alloc((size_t)N * 2 * 4);
  float* er      = (float*)alloc((size_t)N * 2 * 4);
  int*   blocksum = (int*)alloc((size_t)256 * 4);
  int*   blockoff = (int*)alloc((size_t)256 * 4);
  unsigned short* Whi = (unsigned short*)alloc((size_t)65536 * 2);
  unsigned short* Wlo = (unsigned short*)alloc((size_t)65536 * 2);

  const int nb = (N + 1023) / 1024;  // 49

  // CSR by dst (dst invariant across layers: build once)
  hipMemsetAsync(counts, 0, (size_t)N * 4, stream);
  hist_kernel<<<dim3((E + 255) / 256), dim3(256), 0, stream>>>(dst, counts, E);
  scan1_kernel<<<dim3(nb), dim3(256), 0, stream>>>(counts, blocksum, N);
  scan2_kernel<<<dim3(1), dim3(256), 0, stream>>>(blocksum, blockoff, nb, offsets, N);
  scan3_kernel<<<dim3(nb), dim3(256), 0, stream>>>(counts, blockoff, offsets, cursor, N);
  scatter_kernel<<<dim3((E + 255) / 256), dim3(256), 0, stream>>>(dst, cursor, perm, E);

  // pack W (both layers) into MFMA B-fragment order, bf16 hi/lo
  wpack_kernel<<<dim3(32), dim3(256), 0, stream>>>(Ws, Whi, Wlo);

  for (int l = 0; l < 2; ++l) {
    const float* hin = (l == 0) ? x : hbuf;
    const float* al  = als + (size_t)l * 256;
    const float* ar  = ars + (size_t)l * 256;
    const float* b   = bs  + (size_t)l * 256;
    gemm_feat_kernel<<<dim3((N + 63) / 64), dim3(256), 0, stream>>>(
        hin, Whi + (size_t)l * 32768, Wlo + (size_t)l * 32768,
        al, ar, featb, el, er, N);
    eprep_kernel<<<dim3((E + 255) / 256), dim3(256), 0, stream>>>(perm, src, dst, el, er, evp, srcp, E);
    aggregate_kernel<<<dim3((N + 3) / 4), dim3(256), 0, stream>>>(
        featb, evp, srcp, offsets, b,
        (l == 1) ? out : nullptr,
        (l == 0) ? hbuf : nullptr, N);
  }
}

// Round 5
// 295.192 us; speedup vs baseline: 2.2226x; 1.1711x over previous
//
#include <hip/hip_runtime.h>
#include <hip/hip_bf16.h>

// GAT 2-layer, N=50000, E=800000, D=128, H=2, F=128, C=H*F=256.
// Round 5: drop softmax max-shift (mathematically cancels in alpha; exp range
// safe), fuse edge-score computation into aggregate (eprep + evp + perm
// eliminated; scatter writes srcp directly), 1 exp/lane/edge, 4-edge unroll.
// MFMA bf16x3 GEMM and CSR build otherwise unchanged from round 4.

#define NEG_SLOPE 0.2f

typedef __attribute__((ext_vector_type(8))) short bf16x8_t;
typedef __attribute__((ext_vector_type(4))) float f32x4_t;

__device__ __forceinline__ unsigned short f2bf(float f) {
  union { float f; unsigned int u; } v; v.f = f;
  unsigned int r = v.u + 0x7FFFu + ((v.u >> 16) & 1u);
  return (unsigned short)(r >> 16);
}
__device__ __forceinline__ float bfbits(unsigned int hi16) {
  union { unsigned int u; float f; } v; v.u = hi16;
  return v.f;
}

// ---------------- CSR build ----------------

__global__ void hist_kernel(const int* __restrict__ dst, int* __restrict__ counts, int n_edges) {
  int e = blockIdx.x * blockDim.x + threadIdx.x;
  if (e < n_edges) atomicAdd(&counts[dst[e]], 1);
}

__global__ __launch_bounds__(256) void scan1_kernel(const int* __restrict__ counts,
                                                    int* __restrict__ blocksum, int n) {
  __shared__ int wsum[4];
  int t = threadIdx.x;
  int i0 = blockIdx.x * 1024 + t * 4;
  int s = 0;
  if (i0 + 3 < n) {
    int4 c = *(const int4*)&counts[i0];
    s = c.x + c.y + c.z + c.w;
  } else {
    #pragma unroll
    for (int i = 0; i < 4; ++i) if (i0 + i < n) s += counts[i0 + i];
  }
  int v = s;
  #pragma unroll
  for (int off = 1; off < 64; off <<= 1) v += __shfl_xor(v, off);
  if ((t & 63) == 0) wsum[t >> 6] = v;
  __syncthreads();
  if (t == 0) blocksum[blockIdx.x] = wsum[0] + wsum[1] + wsum[2] + wsum[3];
}

__global__ __launch_bounds__(256) void scan2_kernel(const int* __restrict__ blocksum,
                                                    int* __restrict__ blockoff, int nb,
                                                    int* __restrict__ offsets, int n) {
  __shared__ int wsum[4];
  int t = threadIdx.x;
  int v = (t < nb) ? blocksum[t] : 0;
  int lane = t & 63, wid = t >> 6;
  int inc = v;
  #pragma unroll
  for (int off = 1; off < 64; off <<= 1) {
    int u = __shfl_up(inc, off);
    if (lane >= off) inc += u;
  }
  if (lane == 63) wsum[wid] = inc;
  __syncthreads();
  int wbase = 0;
  for (int w = 0; w < wid; ++w) wbase += wsum[w];
  if (t < nb) blockoff[t] = wbase + inc - v;   // exclusive
  if (t == 255) offsets[n] = wbase + inc;      // grand total
}

__global__ __launch_bounds__(256) void scan3_kernel(const int* __restrict__ counts,
                                                    const int* __restrict__ blockoff,
                                                    int* __restrict__ offsets,
                                                    int* __restrict__ cursor, int n) {
  __shared__ int wsum[4];
  int t = threadIdx.x;
  int i0 = blockIdx.x * 1024 + t * 4;
  int c0 = 0, c1 = 0, c2 = 0, c3 = 0;
  if (i0 + 3 < n) {
    int4 c = *(const int4*)&counts[i0];
    c0 = c.x; c1 = c.y; c2 = c.z; c3 = c.w;
  } else {
    if (i0 + 0 < n) c0 = counts[i0 + 0];
    if (i0 + 1 < n) c1 = counts[i0 + 1];
    if (i0 + 2 < n) c2 = counts[i0 + 2];
    if (i0 + 3 < n) c3 = counts[i0 + 3];
  }
  int s = c0 + c1 + c2 + c3;
  int lane = t & 63, wid = t >> 6;
  int inc = s;
  #pragma unroll
  for (int off = 1; off < 64; off <<= 1) {
    int u = __shfl_up(inc, off);
    if (lane >= off) inc += u;
  }
  if (lane == 63) wsum[wid] = inc;
  __syncthreads();
  int wbase = 0;
  for (int w = 0; w < wid; ++w) wbase += wsum[w];
  int o0 = blockoff[blockIdx.x] + wbase + (inc - s);
  int o1 = o0 + c0, o2 = o1 + c1, o3 = o2 + c2;
  if (i0 + 3 < n) {
    *(int4*)&offsets[i0] = make_int4(o0, o1, o2, o3);
    *(int4*)&cursor[i0]  = make_int4(o0, o1, o2, o3);
  } else {
    if (i0 + 0 < n) { offsets[i0 + 0] = o0; cursor[i0 + 0] = o0; }
    if (i0 + 1 < n) { offsets[i0 + 1] = o1; cursor[i0 + 1] = o1; }
    if (i0 + 2 < n) { offsets[i0 + 2] = o2; cursor[i0 + 2] = o2; }
    if (i0 + 3 < n) { offsets[i0 + 3] = o3; cursor[i0 + 3] = o3; }
  }
}

// scatter: writes src id directly into CSR slot (perm eliminated)
__global__ void scatter_kernel(const int* __restrict__ src, const int* __restrict__ dst,
                               int* __restrict__ cursor, int* __restrict__ srcp, int n_edges) {
  int e = blockIdx.x * blockDim.x + threadIdx.x;
  if (e < n_edges) {
    int p = atomicAdd(&cursor[dst[e]], 1);
    srcp[p] = src[e];
  }
}

// ---------------- W pack: fp32 -> bf16 hi/lo in B-fragment order ----------------

__global__ __launch_bounds__(256) void wpack_kernel(const float* __restrict__ Ws,
                                                    unsigned short* __restrict__ Whi,
                                                    unsigned short* __restrict__ Wlo) {
  int t = blockIdx.x * 256 + threadIdx.x;   // 8192 threads: 2 lay x 4 s x 16 ct x 64 lane
  int lane = t & 63;
  int ct = (t >> 6) & 15;
  int s = (t >> 10) & 3;
  int lay = t >> 12;
  int col = ct * 16 + (lane & 15);
  int kbase = s * 32 + (lane >> 4) * 8;
  size_t obase = (size_t)t * 8;
  #pragma unroll
  for (int j = 0; j < 8; ++j) {
    float w = Ws[(size_t)lay * 32768 + (size_t)(kbase + j) * 256 + col];
    unsigned short hb = f2bf(w);
    float rem = w - bfbits((unsigned int)hb << 16);
    Whi[obase + j] = hb;
    Wlo[obase + j] = f2bf(rem);
  }
}

// ---------------- MFMA GEMM: feat = h @ W (bf16x3), fused el/er ----------------

__global__ __launch_bounds__(256) void gemm_feat_kernel(
    const float* __restrict__ hin,
    const unsigned short* __restrict__ Whi, const unsigned short* __restrict__ Wlo,
    const float* __restrict__ al, const float* __restrict__ ar,
    unsigned short* __restrict__ featb, float* __restrict__ el, float* __restrict__ er,
    int n_nodes)
{
  const int tid = threadIdx.x;
  const int w = tid >> 6;
  const int lane = tid & 63;
  const int lrow = lane & 15;
  const int g = lane >> 4;
  const int node0 = blockIdx.x * 64 + w * 16;

  f32x4_t acc[16];
  #pragma unroll
  for (int i = 0; i < 16; ++i) acc[i] = (f32x4_t){0.f, 0.f, 0.f, 0.f};

  int arow = node0 + lrow;
  int arow_c = (arow < n_nodes) ? arow : (n_nodes - 1);
  const float* aptr = hin + (size_t)arow_c * 128 + g * 8;

  for (int s = 0; s < 4; ++s) {
    float4 f0 = *(const float4*)(aptr + s * 32);
    float4 f1 = *(const float4*)(aptr + s * 32 + 4);
    float fv[8] = {f0.x, f0.y, f0.z, f0.w, f1.x, f1.y, f1.z, f1.w};
    bf16x8_t ahi, alo;
    #pragma unroll
    for (int j = 0; j < 8; ++j) {
      unsigned short hb = f2bf(fv[j]);
      float rem = fv[j] - bfbits((unsigned int)hb << 16);
      ahi[j] = (short)hb;
      alo[j] = (short)f2bf(rem);
    }
    const unsigned short* bh_p = Whi + ((size_t)(s * 16) * 64 + lane) * 8;
    const unsigned short* bl_p = Wlo + ((size_t)(s * 16) * 64 + lane) * 8;
    #pragma unroll
    for (int ct = 0; ct < 16; ++ct) {
      bf16x8_t bh = *(const bf16x8_t*)(bh_p + (size_t)ct * 512);
      bf16x8_t bl = *(const bf16x8_t*)(bl_p + (size_t)ct * 512);
      acc[ct] = __builtin_amdgcn_mfma_f32_16x16x32_bf16(ahi, bh, acc[ct], 0, 0, 0);
      acc[ct] = __builtin_amdgcn_mfma_f32_16x16x32_bf16(alo, bh, acc[ct], 0, 0, 0);
      acc[ct] = __builtin_amdgcn_mfma_f32_16x16x32_bf16(ahi, bl, acc[ct], 0, 0, 0);
    }
  }

  float alc[16], arc[16];
  #pragma unroll
  for (int ct = 0; ct < 16; ++ct) {
    alc[ct] = al[ct * 16 + lrow];
    arc[ct] = ar[ct * 16 + lrow];
  }
  #pragma unroll
  for (int r = 0; r < 4; ++r) {
    int orow = node0 + g * 4 + r;
    bool ok = orow < n_nodes;
    float pl0 = 0.f, pl1 = 0.f, pr0 = 0.f, pr1 = 0.f;
    #pragma unroll
    for (int ct = 0; ct < 16; ++ct) {
      float v = acc[ct][r];
      if (ct < 8) { pl0 += v * alc[ct]; pr0 += v * arc[ct]; }
      else        { pl1 += v * alc[ct]; pr1 += v * arc[ct]; }
      if (ok) featb[(size_t)orow * 256 + ct * 16 + lrow] = f2bf(v);
    }
    #pragma unroll
    for (int off = 1; off < 16; off <<= 1) {
      pl0 += __shfl_xor(pl0, off);
      pl1 += __shfl_xor(pl1, off);
      pr0 += __shfl_xor(pr0, off);
      pr1 += __shfl_xor(pr1, off);
    }
    if (lrow == 0 && ok) {
      *(float2*)&el[(size_t)orow * 2] = make_float2(pl0, pl1);
      *(float2*)&er[(size_t)orow * 2] = make_float2(pr0, pr1);
    }
  }
}

// ---------------- fused score + aggregation (no max shift) ----------------
// Per wave: one node. Per edge: e = leaky(el[s] + er[node]) per head,
// xs = exp(min(e,60)); den accumulated per-lane (identical within half-wave).
// lane layout over 256 cols: col = lane*4+i; lanes 0-31 = head 0.

__global__ __launch_bounds__(256) void aggregate_kernel(
    const unsigned short* __restrict__ featb,
    const float* __restrict__ el, const float* __restrict__ er,
    const int* __restrict__ srcp, const int* __restrict__ offsets,
    const float* __restrict__ b,
    float* __restrict__ out, float* __restrict__ hnext, int n_nodes)
{
  int node = blockIdx.x * 4 + (threadIdx.x >> 6);
  int lane = threadIdx.x & 63;
  if (node >= n_nodes) return;
  int beg = offsets[node];
  int end = offsets[node + 1];

  float2 ern = *(const float2*)&er[(size_t)node * 2];
  const bool h0 = (lane < 32);
  const float er_m = h0 ? ern.x : ern.y;

  float4 acc = make_float4(0.f, 0.f, 0.f, 0.f);
  float den = 0.f;

  int j = beg;
  for (; j + 4 <= end; j += 4) {
    int s0 = srcp[j], s1 = srcp[j + 1], s2 = srcp[j + 2], s3 = srcp[j + 3];
    float2 l0 = *(const float2*)&el[(size_t)s0 * 2];
    float2 l1 = *(const float2*)&el[(size_t)s1 * 2];
    float2 l2 = *(const float2*)&el[(size_t)s2 * 2];
    float2 l3 = *(const float2*)&el[(size_t)s3 * 2];
    uint2 q0 = *(const uint2*)&featb[(size_t)s0 * 256 + lane * 4];
    uint2 q1 = *(const uint2*)&featb[(size_t)s1 * 256 + lane * 4];
    uint2 q2 = *(const uint2*)&featb[(size_t)s2 * 256 + lane * 4];
    uint2 q3 = *(const uint2*)&featb[(size_t)s3 * 256 + lane * 4];
    float e0 = (h0 ? l0.x : l0.y) + er_m;
    float e1 = (h0 ? l1.x : l1.y) + er_m;
    float e2 = (h0 ? l2.x : l2.y) + er_m;
    float e3 = (h0 ? l3.x : l3.y) + er_m;
    e0 = fminf((e0 >= 0.f) ? e0 : NEG_SLOPE * e0, 60.f);
    e1 = fminf((e1 >= 0.f) ? e1 : NEG_SLOPE * e1, 60.f);
    e2 = fminf((e2 >= 0.f) ? e2 : NEG_SLOPE * e2, 60.f);
    e3 = fminf((e3 >= 0.f) ? e3 : NEG_SLOPE * e3, 60.f);
    float x0 = __expf(e0), x1 = __expf(e1), x2 = __expf(e2), x3 = __expf(e3);
    den += (x0 + x1) + (x2 + x3);
    acc.x = fmaf(x0, bfbits(q0.x << 16), acc.x);
    acc.y = fmaf(x0, bfbits(q0.x & 0xFFFF0000u), acc.y);
    acc.z = fmaf(x0, bfbits(q0.y << 16), acc.z);
    acc.w = fmaf(x0, bfbits(q0.y & 0xFFFF0000u), acc.w);
    acc.x = fmaf(x1, bfbits(q1.x << 16), acc.x);
    acc.y = fmaf(x1, bfbits(q1.x & 0xFFFF0000u), acc.y);
    acc.z = fmaf(x1, bfbits(q1.y << 16), acc.z);
    acc.w = fmaf(x1, bfbits(q1.y & 0xFFFF0000u), acc.w);
    acc.x = fmaf(x2, bfbits(q2.x << 16), acc.x);
    acc.y = fmaf(x2, bfbits(q2.x & 0xFFFF0000u), acc.y);
    acc.z = fmaf(x2, bfbits(q2.y << 16), acc.z);
    acc.w = fmaf(x2, bfbits(q2.y & 0xFFFF0000u), acc.w);
    acc.x = fmaf(x3, bfbits(q3.x << 16), acc.x);
    acc.y = fmaf(x3, bfbits(q3.x & 0xFFFF0000u), acc.y);
    acc.z = fmaf(x3, bfbits(q3.y << 16), acc.z);
    acc.w = fmaf(x3, bfbits(q3.y & 0xFFFF0000u), acc.w);
  }
  for (; j < end; ++j) {
    int s0 = srcp[j];
    float2 l0 = *(const float2*)&el[(size_t)s0 * 2];
    uint2 q0 = *(const uint2*)&featb[(size_t)s0 * 256 + lane * 4];
    float e0 = (h0 ? l0.x : l0.y) + er_m;
    e0 = fminf((e0 >= 0.f) ? e0 : NEG_SLOPE * e0, 60.f);
    float x0 = __expf(e0);
    den += x0;
    acc.x = fmaf(x0, bfbits(q0.x << 16), acc.x);
    acc.y = fmaf(x0, bfbits(q0.x & 0xFFFF0000u), acc.y);
    acc.z = fmaf(x0, bfbits(q0.y << 16), acc.z);
    acc.w = fmaf(x0, bfbits(q0.y & 0xFFFF0000u), acc.w);
  }

  float4 b4 = *(const float4*)&b[lane * 4];
  float4 o;
  if (end > beg) {
    float inv = 1.0f / den;
    o.x = fmaf(acc.x, inv, b4.x);
    o.y = fmaf(acc.y, inv, b4.y);
    o.z = fmaf(acc.z, inv, b4.z);
    o.w = fmaf(acc.w, inv, b4.w);
  } else {
    o = b4;
  }
  if (out) *(float4*)&out[(size_t)node * 256 + lane * 4] = o;
  if (hnext) {
    float px = __shfl_xor(o.x, 32);
    float py = __shfl_xor(o.y, 32);
    float pz = __shfl_xor(o.z, 32);
    float pw = __shfl_xor(o.w, 32);
    if (lane < 32) {
      float4 hn = make_float4((o.x + px) * 0.5f, (o.y + py) * 0.5f,
                              (o.z + pz) * 0.5f, (o.w + pw) * 0.5f);
      *(float4*)&hnext[(size_t)node * 128 + lane * 4] = hn;
    }
  }
}

// ---------------- launch ----------------

extern "C" void kernel_launch(void* const* d_in, const int* in_sizes, int n_in,
                              void* d_out, int out_size, void* d_ws, size_t ws_size,
                              hipStream_t stream) {
  const float* x   = (const float*)d_in[0];
  const float* Ws  = (const float*)d_in[1];
  const float* als = (const float*)d_in[2];
  const float* ars = (const float*)d_in[3];
  const float* bs  = (const float*)d_in[4];
  const int*   src = (const int*)d_in[5];
  const int*   dst = (const int*)d_in[6];
  const int N = in_sizes[0] / 128;   // 50000
  const int E = in_sizes[5];         // 800000
  float* out = (float*)d_out;

  char* ws = (char*)d_ws;
  auto alloc = [&](size_t bytes) {
    char* p = ws;
    ws += (bytes + 255) & ~(size_t)255;
    return p;
  };
  unsigned short* featb = (unsigned short*)alloc((size_t)N * 256 * 2);
  float* hbuf    = (float*)alloc((size_t)N * 128 * 4);
  int*   srcp    = (int*)alloc((size_t)E * 4);
  int*   offsets = (int*)alloc((size_t)(N + 1) * 4);
  int*   cursor  = (int*)alloc((size_t)N * 4);
  int*   counts  = (int*)alloc((size_t)N * 4);
  float* el      = (float*)alloc((size_t)N * 2 * 4);
  float* er      = (float*)alloc((size_t)N * 2 * 4);
  int*   blocksum = (int*)alloc((size_t)256 * 4);
  int*   blockoff = (int*)alloc((size_t)256 * 4);
  unsigned short* Whi = (unsigned short*)alloc((size_t)65536 * 2);
  unsigned short* Wlo = (unsigned short*)alloc((size_t)65536 * 2);

  const int nb = (N + 1023) / 1024;  // 49

  // CSR by dst (dst invariant across layers: build once)
  hipMemsetAsync(counts, 0, (size_t)N * 4, stream);
  hist_kernel<<<dim3((E + 255) / 256), dim3(256), 0, stream>>>(dst, counts, E);
  scan1_kernel<<<dim3(nb), dim3(256), 0, stream>>>(counts, blocksum, N);
  scan2_kernel<<<dim3(1), dim3(256), 0, stream>>>(blocksum, blockoff, nb, offsets, N);
  scan3_kernel<<<dim3(nb), dim3(256), 0, stream>>>(counts, blockoff, offsets, cursor, N);
  scatter_kernel<<<dim3((E + 255) / 256), dim3(256), 0, stream>>>(src, dst, cursor, srcp, E);

  // pack W (both layers) into MFMA B-fragment order, bf16 hi/lo
  wpack_kernel<<<dim3(32), dim3(256), 0, stream>>>(Ws, Whi, Wlo);

  for (int l = 0; l < 2; ++l) {
    const float* hin = (l == 0) ? x : hbuf;
    const float* al  = als + (size_t)l * 256;
    const float* ar  = ars + (size_t)l * 256;
    const float* b   = bs  + (size_t)l * 256;
    gemm_feat_kernel<<<dim3((N + 63) / 64), dim3(256), 0, stream>>>(
        hin, Whi + (size_t)l * 32768, Wlo + (size_t)l * 32768,
        al, ar, featb, el, er, N);
    aggregate_kernel<<<dim3((N + 3) / 4), dim3(256), 0, stream>>>(
        featb, el, er, srcp, offsets, b,
        (l == 1) ? out : nullptr,
        (l == 0) ? hbuf : nullptr, N);
  }
}